// Round 4
// baseline (691.942 us; speedup 1.0000x reference)
//
#include <hip/hip_runtime.h>

// MeanAggregator: out[b,:] = features[nodes[b],:] + mean_k features[neigh_idx[b,k],:]
// features: [1M, 128] f32, nodes: [B] i32, neigh_idx: [B, 16] i32, out: [B, 128] f32
// Memory-bound random gather. One 32-lane group per output row, f32x4 per lane:
// each row read is a single coalesced 512B burst (full cache-line utilization).

typedef float f32x4 __attribute__((ext_vector_type(4)));   // native vector: works with
typedef int   i32x4 __attribute__((ext_vector_type(4)));   // __builtin_nontemporal_store

constexpr int FEAT_DIM = 128;
constexpr int FEAT_Q   = FEAT_DIM / 4;  // f32x4 chunks per row = 32
constexpr int K        = 16;            // num_sample (fixed by problem setup)

__global__ __launch_bounds__(256) void mean_agg_kernel(
    const float*  __restrict__ features,
    const int*    __restrict__ nodes,
    const int*    __restrict__ neigh_idx,
    float*        __restrict__ out,
    int batch)
{
    const int t = blockIdx.x * blockDim.x + threadIdx.x;
    const int b = t >> 5;            // output row
    if (b >= batch) return;
    const int cq = t & 31;           // f32x4 column chunk, 0..31

    // Indices: 16 neighbors as 4x i32x4 + 1 node id. Uniform address within the
    // 32-lane group -> HW broadcast, negligible traffic (~7 MB total ideal).
    const i32x4* ni = reinterpret_cast<const i32x4*>(neigh_idx) + (size_t)b * (K / 4);
    const i32x4 i0 = ni[0];
    const i32x4 i1 = ni[1];
    const i32x4 i2 = ni[2];
    const i32x4 i3 = ni[3];
    const int   nd = nodes[b];

    const f32x4* f4 = reinterpret_cast<const f32x4*>(features);

    // 17 independent gathered 16B loads -> deep MLP (memory-level parallelism).
    auto row = [&](int idx) -> f32x4 {
        return f4[(size_t)idx * FEAT_Q + cq];
    };

    const f32x4 nf = row(nd);
    const f32x4 a0  = row(i0.x), a1  = row(i0.y), a2  = row(i0.z), a3  = row(i0.w);
    const f32x4 a4  = row(i1.x), a5  = row(i1.y), a6  = row(i1.z), a7  = row(i1.w);
    const f32x4 a8  = row(i2.x), a9  = row(i2.y), a10 = row(i2.z), a11 = row(i2.w);
    const f32x4 a12 = row(i3.x), a13 = row(i3.y), a14 = row(i3.z), a15 = row(i3.w);

    // Pairwise tree sum (vector ops on native vectors).
    const f32x4 s =
        (((a0 + a1) + (a2 + a3)) + ((a4 + a5) + (a6 + a7))) +
        (((a8 + a9) + (a10 + a11)) + ((a12 + a13) + (a14 + a15)));

    constexpr float inv_k = 1.0f / (float)K;
    const f32x4 r = nf + s * inv_k;

    // Output is write-once: nontemporal store keeps L2/L3 free for the gather.
    f32x4* op = reinterpret_cast<f32x4*>(out) + (size_t)b * FEAT_Q + cq;
    __builtin_nontemporal_store(r, op);
}

extern "C" void kernel_launch(void* const* d_in, const int* in_sizes, int n_in,
                              void* d_out, int out_size, void* d_ws, size_t ws_size,
                              hipStream_t stream) {
    const float* features  = (const float*)d_in[0];
    const int*   nodes     = (const int*)d_in[1];
    const int*   neigh_idx = (const int*)d_in[2];
    // d_in[3] = num_sample scalar (always 16 per problem setup) — hard-coded as K.
    float* out = (float*)d_out;

    const int batch = in_sizes[1];              // 100,000
    const int total_threads = batch * 32;       // 32 lanes per output row
    const int block = 256;
    const int grid  = (total_threads + block - 1) / block;

    mean_agg_kernel<<<grid, block, 0, stream>>>(features, nodes, neigh_idx, out, batch);
}